// Round 6
// baseline (689.819 us; speedup 1.0000x reference)
//
#include <hip/hip_runtime.h>

// Round 6: latency-hiding + phase-trim on the MFMA design.
//  - grid 512, 4 batch/WG, 2 WGs/CU (launch_bounds(512,4)) -> 4 waves/SIMD TLP
//  - layer 4 = MFMA (w_ih4 packed as A-frag), software-pipelined into next
//    step's ActA phase (wave 0 only, lane-local finish, no shfl/l4p/barrier)
//  - 5 barriers/step via 3 rotating gl buffers; gl transposed [b][row] so each
//    MFMA tile stores with ONE b128 write; xh stride 80 halves (2/bank quads)

typedef _Float16 f16x8 __attribute__((ext_vector_type(8)));
typedef float    f32x4 __attribute__((ext_vector_type(4)));

constexpr int BATCH   = 2048;
constexpr int T_STEPS = 256;
constexpr int H   = 51;
constexpr int G4  = 204;                  // 4*H gate rows
constexpr int NTILE = 13;                 // 16-row tiles (208 padded)
constexpr int NUNIT = 5 * NTILE * 2 + 2;  // 130 big + 2 layer-4 units = 132
constexpr int XKP = 80;                   // xh row stride in halves (160 B)
constexpr int GLR = 212;                  // gl row stride in dwords

__device__ __forceinline__ float frcp(float x) { return __builtin_amdgcn_rcpf(x); }
__device__ __forceinline__ float sigmoid_f(float x) { float e = __expf(-x); return frcp(1.f + e); }
__device__ __forceinline__ float tanh_f(float x) {
    float xc = fminf(fmaxf(x, -15.f), 15.f);
    float e = __expf(2.f * xc);
    return 1.f - 2.f * frcp(e + 1.f);
}

// Pack weights into MFMA A-fragment layout (fp16).
// u<130: u=(pm*13+tile)*2+kf, pm: 0=hh1(+w_ih1 col at k=51) 1=ih2 2=hh2 3=ih3 4=hh3
// u=130/131: layer-4 w_ih4 (rows 0-3), kf = u-130.
__global__ __launch_bounds__(256) void prep_mfma(
    const float* __restrict__ w_ih1, const float* __restrict__ w_hh1,
    const float* __restrict__ w_ih2, const float* __restrict__ w_hh2,
    const float* __restrict__ w_ih3, const float* __restrict__ w_hh3,
    const float* __restrict__ w_ih4, _Float16* __restrict__ wpa)
{
    int id = blockIdx.x * 256 + threadIdx.x;
    if (id >= NUNIT * 64) return;
    int u = id >> 6, l = id & 63;
    int row16 = l & 15;
    int kbase = ((u & 1) ? 32 : 0) + ((l >> 4) << 3);
    f16x8 v;
    if (u < 130) {
        int pm = u / 26, tile = (u % 26) >> 1;
        const float* W = (pm == 0) ? w_hh1 : (pm == 1) ? w_ih2 : (pm == 2) ? w_hh2
                       : (pm == 3) ? w_ih3 : w_hh3;
        int row = tile * 16 + row16;
#pragma unroll
        for (int e = 0; e < 8; ++e) {
            int k = kbase + e;
            float val = 0.f;
            if (row < G4) {
                if (k < H)                  val = W[row * H + k];
                else if (k == H && pm == 0) val = w_ih1[row];
            }
            v[e] = (_Float16)val;
        }
    } else {
#pragma unroll
        for (int e = 0; e < 8; ++e) {
            int k = kbase + e;
            v[e] = (_Float16)((row16 < 4 && k < H) ? w_ih4[row16 * H + k] : 0.f);
        }
    }
    *(f16x8*)(wpa + (size_t)u * 512 + l * 8) = v;
}

__global__ __launch_bounds__(512, 4) void lstm4_main(
    const float* __restrict__ input, const _Float16* __restrict__ wpa,
    const float* __restrict__ b_ih1, const float* __restrict__ b_hh1,
    const float* __restrict__ b_ih2, const float* __restrict__ b_hh2,
    const float* __restrict__ b_ih3, const float* __restrict__ b_hh3,
    const float* __restrict__ w_hh4,
    const float* __restrict__ b_ih4, const float* __restrict__ b_hh4,
    float* __restrict__ out)
{
    // xh vectors (fp16): 0=h1(+x at k=51) 1=c1 2=h2 3=c2 4=h3 5=c3
    __shared__ __align__(16) _Float16 xh[6][4][XKP];   // 3840 B
    __shared__ float gl[3][4][GLR];                    // 10176 B (3 rotating bufs)
    __shared__ float inl[4 * 260];                     // 4160 B

    const int tid  = threadIdx.x;
    const int wave = tid >> 6;
    const int lane = tid & 63;
    const int col  = lane & 15;    // mfma C/D col
    const int rg   = lane >> 4;    // mfma row-group / k-group
    const int bcol = lane & 3;     // batch col for B-frag reads (cols 4-15 dup)
    const int k    = tid >> 3;     // act: hidden unit 0..63
    const int b    = tid & 7;      // act: batch candidate
    const int bc   = b & 3;
    const bool act_on = (k < H) && (b < 4);
    const int  kc  = (k < H) ? k : (H - 1);

    // ---- persistent weight fragments ----
    const int tile0 = wave;
    const int tile1 = (wave < 5) ? (8 + wave) : wave;
    const bool two  = (wave < 5);
    auto LF = [&](int pm, int tile, int kf) -> f16x8 {
        int u = (pm * NTILE + tile) * 2 + kf;
        return *(const f16x8*)(wpa + (size_t)u * 512 + lane * 8);
    };
    const f16x8 fA_0k0  = LF(0, tile0, 0), fA_0k1  = LF(0, tile0, 1);
    const f16x8 fA_1k0  = LF(0, tile1, 0), fA_1k1  = LF(0, tile1, 1);
    const f16x8 fI2_0k0 = LF(1, tile0, 0), fI2_0k1 = LF(1, tile0, 1);
    const f16x8 fI2_1k0 = LF(1, tile1, 0), fI2_1k1 = LF(1, tile1, 1);
    const f16x8 fH2_0k0 = LF(2, tile0, 0), fH2_0k1 = LF(2, tile0, 1);
    const f16x8 fH2_1k0 = LF(2, tile1, 0), fH2_1k1 = LF(2, tile1, 1);
    const f16x8 fI3_0k0 = LF(3, tile0, 0), fI3_0k1 = LF(3, tile0, 1);
    const f16x8 fI3_1k0 = LF(3, tile1, 0), fI3_1k1 = LF(3, tile1, 1);
    const f16x8 fH3_0k0 = LF(4, tile0, 0), fH3_0k1 = LF(4, tile0, 1);
    const f16x8 fH3_1k0 = LF(4, tile1, 0), fH3_1k1 = LF(4, tile1, 1);
    const f16x8 fL4k0 = *(const f16x8*)(wpa + (size_t)130 * 512 + lane * 8);
    const f16x8 fL4k1 = *(const f16x8*)(wpa + (size_t)131 * 512 + lane * 8);

    // ---- per-lane constants ----
    float acb1[4], acb2[4], acb3[4], bias4v[4], whh4v[4];
#pragma unroll
    for (int q = 0; q < 4; ++q) {
        const int r = q * H + kc;
        acb1[q] = b_ih1[r] + b_hh1[r];
        acb2[q] = b_ih2[r] + b_hh2[r];
        acb3[q] = b_ih3[r] + b_hh3[r];
        bias4v[q] = b_ih4[q] + b_hh4[q];
        whh4v[q]  = w_hh4[q];
    }

    // ---- stage input, zero x-vectors ----
    if (tid < 256) {
        const float4 iv = *(const float4*)(input + (size_t)blockIdx.x * 1024 + tid * 4);
        *(float4*)(inl + (tid >> 6) * 260 + (tid & 63) * 4) = iv;
    }
    for (int i = tid; i < 6 * 4 * XKP; i += 512) ((_Float16*)xh)[i] = (_Float16)0.f;
    __syncthreads();
    if (tid < 4) xh[0][tid][H] = (_Float16)inl[tid * 260];   // x for t=0
    __syncthreads();

    float c1r = 0.f, c2r = 0.f, c3r = 0.f;
    float h4 = 0.f, c4 = 0.f;   // live on wave 0, lanes 0-3 (lane = batch)

    // layer-4 step: wave 0 only; lane-local finish (lane holds all 4 gates)
    auto do_l4 = [&]() {
        const f16x8 lb0 = *(const f16x8*)&xh[5][bcol][rg * 8];
        const f16x8 lb1 = *(const f16x8*)&xh[5][bcol][32 + rg * 8];
        f32x4 la = {0.f, 0.f, 0.f, 0.f};
        la = __builtin_amdgcn_mfma_f32_16x16x32_f16(fL4k0, lb0, la, 0, 0, 0);
        la = __builtin_amdgcn_mfma_f32_16x16x32_f16(fL4k1, lb1, la, 0, 0, 0);
        if (lane < 4) {
            const float i_ = sigmoid_f(la[0] + bias4v[0] + whh4v[0] * h4);
            const float f_ = sigmoid_f(la[1] + bias4v[1] + whh4v[1] * h4);
            const float g_ = tanh_f  (la[2] + bias4v[2] + whh4v[2] * h4);
            const float o_ = sigmoid_f(la[3] + bias4v[3] + whh4v[3] * h4);
            c4 = f_ * c4 + i_ * g_;
            h4 = o_ * tanh_f(c4);
        }
    };

    for (int t = 0; t <= T_STEPS; ++t) {
        // ========== mvA: gates1 = hh1 @ h1 + w_ih1 * x (k=51 col) -> gl[0] ==========
        {
            const f16x8 bv0 = *(const f16x8*)&xh[0][bcol][rg * 8];
            const f16x8 bv1 = *(const f16x8*)&xh[0][bcol][32 + rg * 8];
            f32x4 a0 = {0.f, 0.f, 0.f, 0.f};
            a0 = __builtin_amdgcn_mfma_f32_16x16x32_f16(fA_0k0, bv0, a0, 0, 0, 0);
            a0 = __builtin_amdgcn_mfma_f32_16x16x32_f16(fA_0k1, bv1, a0, 0, 0, 0);
            if (col < 4) *(f32x4*)&gl[0][col][tile0 * 16 + rg * 4] = a0;
            if (two) {
                f32x4 a1 = {0.f, 0.f, 0.f, 0.f};
                a1 = __builtin_amdgcn_mfma_f32_16x16x32_f16(fA_1k0, bv0, a1, 0, 0, 0);
                a1 = __builtin_amdgcn_mfma_f32_16x16x32_f16(fA_1k1, bv1, a1, 0, 0, 0);
                if (col < 4) *(f32x4*)&gl[0][col][tile1 * 16 + rg * 4] = a1;
            }
        }
        __syncthreads();  // B1

        // ========== ActA (+ pipelined layer-4 of step t-1, wave 0) ==========
        if (wave == 0 && t >= 1 && t < T_STEPS) do_l4();
        {
            const float gi = gl[0][bc][0 * H + kc] + acb1[0];
            const float gf = gl[0][bc][1 * H + kc] + acb1[1];
            const float gg = gl[0][bc][2 * H + kc] + acb1[2];
            const float go = gl[0][bc][3 * H + kc] + acb1[3];
            if (act_on) {
                const float i_ = sigmoid_f(gi), f_ = sigmoid_f(gf);
                const float g_ = tanh_f(gg), o_ = sigmoid_f(go);
                c1r = f_ * c1r + i_ * g_;
                const float h1 = o_ * tanh_f(c1r);
                xh[0][b][k] = (_Float16)h1;
                xh[1][b][k] = (_Float16)c1r;
            }
        }
        __syncthreads();  // B2

        // ========== mvB: gates2 = ih2 @ c1 + hh2 @ h2 -> gl[1] ==========
        {
            const f16x8 bx0 = *(const f16x8*)&xh[1][bcol][rg * 8];
            const f16x8 bx1 = *(const f16x8*)&xh[1][bcol][32 + rg * 8];
            const f16x8 bh0 = *(const f16x8*)&xh[2][bcol][rg * 8];
            const f16x8 bh1 = *(const f16x8*)&xh[2][bcol][32 + rg * 8];
            f32x4 a0 = {0.f, 0.f, 0.f, 0.f};
            a0 = __builtin_amdgcn_mfma_f32_16x16x32_f16(fI2_0k0, bx0, a0, 0, 0, 0);
            a0 = __builtin_amdgcn_mfma_f32_16x16x32_f16(fI2_0k1, bx1, a0, 0, 0, 0);
            a0 = __builtin_amdgcn_mfma_f32_16x16x32_f16(fH2_0k0, bh0, a0, 0, 0, 0);
            a0 = __builtin_amdgcn_mfma_f32_16x16x32_f16(fH2_0k1, bh1, a0, 0, 0, 0);
            if (col < 4) *(f32x4*)&gl[1][col][tile0 * 16 + rg * 4] = a0;
            if (two) {
                f32x4 a1 = {0.f, 0.f, 0.f, 0.f};
                a1 = __builtin_amdgcn_mfma_f32_16x16x32_f16(fI2_1k0, bx0, a1, 0, 0, 0);
                a1 = __builtin_amdgcn_mfma_f32_16x16x32_f16(fI2_1k1, bx1, a1, 0, 0, 0);
                a1 = __builtin_amdgcn_mfma_f32_16x16x32_f16(fH2_1k0, bh0, a1, 0, 0, 0);
                a1 = __builtin_amdgcn_mfma_f32_16x16x32_f16(fH2_1k1, bh1, a1, 0, 0, 0);
                if (col < 4) *(f32x4*)&gl[1][col][tile1 * 16 + rg * 4] = a1;
            }
        }
        __syncthreads();  // B3

        // ========== ActB ==========
        {
            const float gi = gl[1][bc][0 * H + kc] + acb2[0];
            const float gf = gl[1][bc][1 * H + kc] + acb2[1];
            const float gg = gl[1][bc][2 * H + kc] + acb2[2];
            const float go = gl[1][bc][3 * H + kc] + acb2[3];
            if (act_on) {
                const float i_ = sigmoid_f(gi), f_ = sigmoid_f(gf);
                const float g_ = tanh_f(gg), o_ = sigmoid_f(go);
                c2r = f_ * c2r + i_ * g_;
                const float h2 = o_ * tanh_f(c2r);
                xh[2][b][k] = (_Float16)h2;
                xh[3][b][k] = (_Float16)c2r;
            }
            // stage next step's x_t (from input; known in advance)
            if (k == H && b < 4 && t + 1 < T_STEPS)
                xh[0][b][H] = (_Float16)inl[b * 260 + t + 1];
        }
        __syncthreads();  // B4

        // ========== mvC: gates3 = ih3 @ c2 + hh3 @ h3 -> gl[2] ==========
        {
            const f16x8 bx0 = *(const f16x8*)&xh[3][bcol][rg * 8];
            const f16x8 bx1 = *(const f16x8*)&xh[3][bcol][32 + rg * 8];
            const f16x8 bh0 = *(const f16x8*)&xh[4][bcol][rg * 8];
            const f16x8 bh1 = *(const f16x8*)&xh[4][bcol][32 + rg * 8];
            f32x4 a0 = {0.f, 0.f, 0.f, 0.f};
            a0 = __builtin_amdgcn_mfma_f32_16x16x32_f16(fI3_0k0, bx0, a0, 0, 0, 0);
            a0 = __builtin_amdgcn_mfma_f32_16x16x32_f16(fI3_0k1, bx1, a0, 0, 0, 0);
            a0 = __builtin_amdgcn_mfma_f32_16x16x32_f16(fH3_0k0, bh0, a0, 0, 0, 0);
            a0 = __builtin_amdgcn_mfma_f32_16x16x32_f16(fH3_0k1, bh1, a0, 0, 0, 0);
            if (col < 4) *(f32x4*)&gl[2][col][tile0 * 16 + rg * 4] = a0;
            if (two) {
                f32x4 a1 = {0.f, 0.f, 0.f, 0.f};
                a1 = __builtin_amdgcn_mfma_f32_16x16x32_f16(fI3_1k0, bx0, a1, 0, 0, 0);
                a1 = __builtin_amdgcn_mfma_f32_16x16x32_f16(fI3_1k1, bx1, a1, 0, 0, 0);
                a1 = __builtin_amdgcn_mfma_f32_16x16x32_f16(fH3_1k0, bh0, a1, 0, 0, 0);
                a1 = __builtin_amdgcn_mfma_f32_16x16x32_f16(fH3_1k1, bh1, a1, 0, 0, 0);
                if (col < 4) *(f32x4*)&gl[2][col][tile1 * 16 + rg * 4] = a1;
            }
        }
        __syncthreads();  // B5

        // ========== ActC (no trailing barrier; gl rotation makes it safe) ==========
        {
            const float gi = gl[2][bc][0 * H + kc] + acb3[0];
            const float gf = gl[2][bc][1 * H + kc] + acb3[1];
            const float gg = gl[2][bc][2 * H + kc] + acb3[2];
            const float go = gl[2][bc][3 * H + kc] + acb3[3];
            if (act_on) {
                const float i_ = sigmoid_f(gi), f_ = sigmoid_f(gf);
                const float g_ = tanh_f(gg), o_ = sigmoid_f(go);
                c3r = f_ * c3r + i_ * g_;
                const float h3 = o_ * tanh_f(c3r);
                xh[4][b][k] = (_Float16)h3;
                xh[5][b][k] = (_Float16)c3r;
            }
        }

        if (t == T_STEPS - 1) {   // eager layer-4(255): its c4 is the extra step's x
            __syncthreads();
            if (wave == 0) {
                do_l4();
                if (lane < 4) xh[0][lane][H] = (_Float16)c4;
            }
            __syncthreads();
        }
    }

    // epilogue: layer-4 of the extra step, then output
    __syncthreads();
    if (wave == 0) {
        do_l4();
        if (lane < 4) out[blockIdx.x * 4 + lane] = c4;
    }
}

extern "C" void kernel_launch(void* const* d_in, const int* in_sizes, int n_in,
                              void* d_out, int out_size, void* d_ws, size_t ws_size,
                              hipStream_t stream) {
    const float* input = (const float*)d_in[0];
    const float* w_ih1 = (const float*)d_in[1];
    const float* w_hh1 = (const float*)d_in[2];
    const float* b_ih1 = (const float*)d_in[3];
    const float* b_hh1 = (const float*)d_in[4];
    const float* w_ih2 = (const float*)d_in[5];
    const float* w_hh2 = (const float*)d_in[6];
    const float* b_ih2 = (const float*)d_in[7];
    const float* b_hh2 = (const float*)d_in[8];
    const float* w_ih3 = (const float*)d_in[9];
    const float* w_hh3 = (const float*)d_in[10];
    const float* b_ih3 = (const float*)d_in[11];
    const float* b_hh3 = (const float*)d_in[12];
    const float* w_ih4 = (const float*)d_in[13];
    const float* w_hh4 = (const float*)d_in[14];
    const float* b_ih4 = (const float*)d_in[15];
    const float* b_hh4 = (const float*)d_in[16];

    _Float16* wpa = (_Float16*)d_ws;  // 132 units * 512 halves = 135,168 B

    hipLaunchKernelGGL(prep_mfma, dim3((NUNIT * 64 + 255) / 256), dim3(256), 0, stream,
                       w_ih1, w_hh1, w_ih2, w_hh2, w_ih3, w_hh3, w_ih4, wpa);

    hipLaunchKernelGGL(lstm4_main, dim3(BATCH / 4), dim3(512), 0, stream,
                       input, wpa,
                       b_ih1, b_hh1, b_ih2, b_hh2, b_ih3, b_hh3,
                       w_hh4, b_ih4, b_hh4,
                       (float*)d_out);
}

// Round 8
// 441.222 us; speedup vs baseline: 1.5634x; 1.5634x over previous
//
#include <hip/hip_runtime.h>

// Round 7 (resubmit after GPU-acquisition timeout): gate-interleaved MFMA tiles ->
// in-register activations, 3 barriers/step.
// Weight rows permuted row' = (k/4)*16 + (k%4)*4 + q so each 16-row tile holds all
// 4 gates of 4 hidden units; MFMA C/D layout then gives lane (col=b, rg) the 4
// gates of unit k=4*kk+rg in acc[0..3] -> act in-reg, no gate-LDS round trip.
// Biases preloaded into the MFMA C operand. B-frags prefetched one phase ahead.
// Layer 4 = MFMA on wave 7, software-pipelined into next step's phase 1.
// WG 512 (8 waves) x 8 batch, grid 256, 1 WG/CU.

typedef _Float16 f16x8 __attribute__((ext_vector_type(8)));
typedef float    f32x4 __attribute__((ext_vector_type(4)));

constexpr int BATCH   = 2048;
constexpr int T_STEPS = 256;
constexpr int H   = 51;
constexpr int NTILE = 13;                 // 16-row tiles (208 padded rows)
constexpr int NUNIT = 5 * NTILE * 2 + 2;  // 130 big + 2 layer-4 units
constexpr int XKP = 80;                   // xh row stride in halves (160 B)

__device__ __forceinline__ float frcp(float x) { return __builtin_amdgcn_rcpf(x); }
__device__ __forceinline__ float sigmoid_f(float x) { float e = __expf(-x); return frcp(1.f + e); }
__device__ __forceinline__ float tanh_f(float x) {
    // no clamp needed: exp(2x)->inf gives 1-0=1; ->0 gives -1
    float e = __expf(2.f * x);
    return 1.f - 2.f * frcp(e + 1.f);
}

// Pack weights into MFMA A-frag layout with gate-interleaved rows.
// u<130: u=(pm*13+tile)*2+kf; pm: 0=hh1(+w_ih1 col at j=51) 1=ih2 2=hh2 3=ih3 4=hh3
//   row16 = (k%4)*4+q with k = tile*4 + row16/4, q = row16%4; orig row = q*H+k.
// u=130/131: layer-4 w_ih4 rows 0-3 (row'=q), kf=u-130.
__global__ __launch_bounds__(256) void prep_mfma(
    const float* __restrict__ w_ih1, const float* __restrict__ w_hh1,
    const float* __restrict__ w_ih2, const float* __restrict__ w_hh2,
    const float* __restrict__ w_ih3, const float* __restrict__ w_hh3,
    const float* __restrict__ w_ih4, _Float16* __restrict__ wpa)
{
    int id = blockIdx.x * 256 + threadIdx.x;
    if (id >= NUNIT * 64) return;
    int u = id >> 6, l = id & 63;
    int row16 = l & 15;
    int kbase = ((u & 1) ? 32 : 0) + ((l >> 4) << 3);
    f16x8 v;
    if (u < 130) {
        int pm = u / 26, tile = (u % 26) >> 1;
        const float* W = (pm == 0) ? w_hh1 : (pm == 1) ? w_ih2 : (pm == 2) ? w_hh2
                       : (pm == 3) ? w_ih3 : w_hh3;
        int kh = tile * 4 + (row16 >> 2);   // hidden unit
        int q  = row16 & 3;                 // gate
        bool rv = (kh < H);
        int orow = q * H + kh;
#pragma unroll
        for (int e = 0; e < 8; ++e) {
            int j = kbase + e;
            float val = 0.f;
            if (rv) {
                if (j < H)                  val = W[orow * H + j];
                else if (j == H && pm == 0) val = w_ih1[orow];   // x_t column
            }
            v[e] = (_Float16)val;
        }
    } else {
#pragma unroll
        for (int e = 0; e < 8; ++e) {
            int j = kbase + e;
            v[e] = (_Float16)((row16 < 4 && j < H) ? w_ih4[row16 * H + j] : 0.f);
        }
    }
    *(f16x8*)(wpa + (size_t)u * 512 + l * 8) = v;
}

__global__ __launch_bounds__(512, 2) void lstm4_main(
    const float* __restrict__ input, const _Float16* __restrict__ wpa,
    const float* __restrict__ b_ih1, const float* __restrict__ b_hh1,
    const float* __restrict__ b_ih2, const float* __restrict__ b_hh2,
    const float* __restrict__ b_ih3, const float* __restrict__ b_hh3,
    const float* __restrict__ w_hh4,
    const float* __restrict__ b_ih4, const float* __restrict__ b_hh4,
    float* __restrict__ out)
{
    // xh vectors (fp16): 0=h1(+x at k=51) 1=c1 2=h2 3=c2 4=h3 5=c3
    __shared__ __align__(16) _Float16 xh[6][8][XKP];   // 7680 B
    __shared__ float inl[8 * 260];                     // 8320 B

    const int tid  = threadIdx.x;
    const int wave = tid >> 6;
    const int lane = tid & 63;
    const int col  = lane & 15;    // mfma C/D col = batch (cols 8-15 duplicate)
    const int rg   = lane >> 4;    // row-group: unit-within-tile / k-group
    const int bcol = lane & 7;     // batch index for B-frag reads

    // ---- persistent weight fragments ----
    const int tile0 = wave;                          // k0 = 4*tile0+rg <= 31 < H always
    const int tile1 = (wave < 5) ? (8 + wave) : wave;
    const bool two  = (wave < 5);
    auto LF = [&](int pm, int tile, int kf) -> f16x8 {
        int u = (pm * NTILE + tile) * 2 + kf;
        return *(const f16x8*)(wpa + (size_t)u * 512 + lane * 8);
    };
    const f16x8 fA_0k0  = LF(0, tile0, 0), fA_0k1  = LF(0, tile0, 1);
    const f16x8 fA_1k0  = LF(0, tile1, 0), fA_1k1  = LF(0, tile1, 1);
    const f16x8 fI2_0k0 = LF(1, tile0, 0), fI2_0k1 = LF(1, tile0, 1);
    const f16x8 fI2_1k0 = LF(1, tile1, 0), fI2_1k1 = LF(1, tile1, 1);
    const f16x8 fH2_0k0 = LF(2, tile0, 0), fH2_0k1 = LF(2, tile0, 1);
    const f16x8 fH2_1k0 = LF(2, tile1, 0), fH2_1k1 = LF(2, tile1, 1);
    const f16x8 fI3_0k0 = LF(3, tile0, 0), fI3_0k1 = LF(3, tile0, 1);
    const f16x8 fI3_1k0 = LF(3, tile1, 0), fI3_1k1 = LF(3, tile1, 1);
    const f16x8 fH3_0k0 = LF(4, tile0, 0), fH3_0k1 = LF(4, tile0, 1);
    const f16x8 fH3_1k0 = LF(4, tile1, 0), fH3_1k1 = LF(4, tile1, 1);
    const f16x8 fL4k0 = *(const f16x8*)(wpa + (size_t)130 * 512 + lane * 8);
    const f16x8 fL4k1 = *(const f16x8*)(wpa + (size_t)131 * 512 + lane * 8);

    // ---- per-lane bias vectors (folded into MFMA C operand) ----
    const int k0 = tile0 * 4 + rg;
    const int k1 = tile1 * 4 + rg;
    const bool k1v = two && (k1 < H);
    f32x4 cb1v0, cb1v1, cb2v0, cb2v1, cb3v0, cb3v1;
#pragma unroll
    for (int q = 0; q < 4; ++q) {
        cb1v0[q] = b_ih1[q * H + k0] + b_hh1[q * H + k0];
        cb2v0[q] = b_ih2[q * H + k0] + b_hh2[q * H + k0];
        cb3v0[q] = b_ih3[q * H + k0] + b_hh3[q * H + k0];
        cb1v1[q] = k1v ? (b_ih1[q * H + k1] + b_hh1[q * H + k1]) : 0.f;
        cb2v1[q] = k1v ? (b_ih2[q * H + k1] + b_hh2[q * H + k1]) : 0.f;
        cb3v1[q] = k1v ? (b_ih3[q * H + k1] + b_hh3[q * H + k1]) : 0.f;
    }
    float bias4v[4], whh4v[4];
#pragma unroll
    for (int q = 0; q < 4; ++q) {
        bias4v[q] = b_ih4[q] + b_hh4[q];
        whh4v[q]  = w_hh4[q];
    }

    // ---- stage input, zero x-vectors ----
    {
        const float4 iv = *(const float4*)(input + (size_t)blockIdx.x * 2048 + tid * 4);
        *(float4*)(inl + (tid >> 6) * 260 + (tid & 63) * 4) = iv;
    }
    for (int i = tid; i < 6 * 8 * XKP; i += 512) ((_Float16*)xh)[i] = (_Float16)0.f;
    __syncthreads();
    if (tid < 8) xh[0][tid][H] = (_Float16)inl[tid * 260];   // x for t=0
    __syncthreads();

    // per-lane cell states (unit k, batch col) and layer-4 state (wave 7, lanes 0-7)
    float c1s0 = 0.f, c1s1 = 0.f, c2s0 = 0.f, c2s1 = 0.f, c3s0 = 0.f, c3s1 = 0.f;
    float h4 = 0.f, c4 = 0.f;

    // in-register activation + h/c store
    auto act_store = [&](f32x4 acc, float& cs, int kidx, bool valid, int vh, int vc) {
        const float i_ = sigmoid_f(acc[0]);
        const float f_ = sigmoid_f(acc[1]);
        const float g_ = tanh_f(acc[2]);
        const float o_ = sigmoid_f(acc[3]);
        cs = f_ * cs + i_ * g_;
        const float h = o_ * tanh_f(cs);
        if (col < 8 && valid) {
            xh[vh][col][kidx] = (_Float16)h;
            xh[vc][col][kidx] = (_Float16)cs;
        }
    };

    auto do_l4 = [&]() {   // wave 7 only; c3 vector from xh[5]
        const f16x8 lb0 = *(const f16x8*)&xh[5][bcol][rg * 8];
        const f16x8 lb1 = *(const f16x8*)&xh[5][bcol][32 + rg * 8];
        f32x4 la = {0.f, 0.f, 0.f, 0.f};
        la = __builtin_amdgcn_mfma_f32_16x16x32_f16(fL4k0, lb0, la, 0, 0, 0);
        la = __builtin_amdgcn_mfma_f32_16x16x32_f16(fL4k1, lb1, la, 0, 0, 0);
        if (lane < 8) {    // col=b, rg=0 -> acc[q] = gate q for batch lane
            const float i_ = sigmoid_f(la[0] + bias4v[0] + whh4v[0] * h4);
            const float f_ = sigmoid_f(la[1] + bias4v[1] + whh4v[1] * h4);
            const float g_ = tanh_f  (la[2] + bias4v[2] + whh4v[2] * h4);
            const float o_ = sigmoid_f(la[3] + bias4v[3] + whh4v[3] * h4);
            c4 = f_ * c4 + i_ * g_;
            h4 = o_ * tanh_f(c4);
        }
    };

    // prefetch phase-1 B-frags (h1 vector + x col)
    f16x8 pA0 = *(const f16x8*)&xh[0][bcol][rg * 8];
    f16x8 pA1 = *(const f16x8*)&xh[0][bcol][32 + rg * 8];

    for (int t = 0; t <= T_STEPS; ++t) {
        // ========== phase 1: layer 1 (+ pipelined L4(t-1) on wave 7) ==========
        const f16x8 pH2a = *(const f16x8*)&xh[2][bcol][rg * 8];        // prefetch h2
        const f16x8 pH2b = *(const f16x8*)&xh[2][bcol][32 + rg * 8];
        if (wave == 7 && t >= 1 && t < T_STEPS) do_l4();
        {
            f32x4 a0 = cb1v0;
            a0 = __builtin_amdgcn_mfma_f32_16x16x32_f16(fA_0k0, pA0, a0, 0, 0, 0);
            a0 = __builtin_amdgcn_mfma_f32_16x16x32_f16(fA_0k1, pA1, a0, 0, 0, 0);
            act_store(a0, c1s0, k0, true, 0, 1);
            if (two) {
                f32x4 a1 = cb1v1;
                a1 = __builtin_amdgcn_mfma_f32_16x16x32_f16(fA_1k0, pA0, a1, 0, 0, 0);
                a1 = __builtin_amdgcn_mfma_f32_16x16x32_f16(fA_1k1, pA1, a1, 0, 0, 0);
                act_store(a1, c1s1, k1, k1 < H, 0, 1);
            }
        }
        __syncthreads();  // B1

        // ========== phase 2: layer 2 (input c1, hidden h2) ==========
        {
            const f16x8 bx0 = *(const f16x8*)&xh[1][bcol][rg * 8];     // c1 (fresh)
            const f16x8 bx1 = *(const f16x8*)&xh[1][bcol][32 + rg * 8];
            const f16x8 pH3a = *(const f16x8*)&xh[4][bcol][rg * 8];    // prefetch h3
            const f16x8 pH3b = *(const f16x8*)&xh[4][bcol][32 + rg * 8];
            if (wave == 6 && lane < 8 && t + 1 < T_STEPS)              // stage next x
                xh[0][lane][H] = (_Float16)inl[lane * 260 + t + 1];
            f32x4 a0 = cb2v0;
            a0 = __builtin_amdgcn_mfma_f32_16x16x32_f16(fH2_0k0, pH2a, a0, 0, 0, 0);
            a0 = __builtin_amdgcn_mfma_f32_16x16x32_f16(fH2_0k1, pH2b, a0, 0, 0, 0);
            a0 = __builtin_amdgcn_mfma_f32_16x16x32_f16(fI2_0k0, bx0, a0, 0, 0, 0);
            a0 = __builtin_amdgcn_mfma_f32_16x16x32_f16(fI2_0k1, bx1, a0, 0, 0, 0);
            act_store(a0, c2s0, k0, true, 2, 3);
            if (two) {
                f32x4 a1 = cb2v1;
                a1 = __builtin_amdgcn_mfma_f32_16x16x32_f16(fH2_1k0, pH2a, a1, 0, 0, 0);
                a1 = __builtin_amdgcn_mfma_f32_16x16x32_f16(fH2_1k1, pH2b, a1, 0, 0, 0);
                a1 = __builtin_amdgcn_mfma_f32_16x16x32_f16(fI2_1k0, bx0, a1, 0, 0, 0);
                a1 = __builtin_amdgcn_mfma_f32_16x16x32_f16(fI2_1k1, bx1, a1, 0, 0, 0);
                act_store(a1, c2s1, k1, k1 < H, 2, 3);
            }
            __syncthreads();  // B2

            // ========== phase 3: layer 3 (input c2, hidden h3) ==========
            const f16x8 cx0 = *(const f16x8*)&xh[3][bcol][rg * 8];     // c2 (fresh)
            const f16x8 cx1 = *(const f16x8*)&xh[3][bcol][32 + rg * 8];
            f32x4 b0 = cb3v0;
            b0 = __builtin_amdgcn_mfma_f32_16x16x32_f16(fH3_0k0, pH3a, b0, 0, 0, 0);
            b0 = __builtin_amdgcn_mfma_f32_16x16x32_f16(fH3_0k1, pH3b, b0, 0, 0, 0);
            b0 = __builtin_amdgcn_mfma_f32_16x16x32_f16(fI3_0k0, cx0, b0, 0, 0, 0);
            b0 = __builtin_amdgcn_mfma_f32_16x16x32_f16(fI3_0k1, cx1, b0, 0, 0, 0);
            act_store(b0, c3s0, k0, true, 4, 5);
            if (two) {
                f32x4 b1 = cb3v1;
                b1 = __builtin_amdgcn_mfma_f32_16x16x32_f16(fH3_1k0, pH3a, b1, 0, 0, 0);
                b1 = __builtin_amdgcn_mfma_f32_16x16x32_f16(fH3_1k1, pH3b, b1, 0, 0, 0);
                b1 = __builtin_amdgcn_mfma_f32_16x16x32_f16(fI3_1k0, cx0, b1, 0, 0, 0);
                b1 = __builtin_amdgcn_mfma_f32_16x16x32_f16(fI3_1k1, cx1, b1, 0, 0, 0);
                act_store(b1, c3s1, k1, k1 < H, 4, 5);
            }
        }
        // prefetch next phase-1 B-frags (h1 written phase 1, x staged phase 2)
        pA0 = *(const f16x8*)&xh[0][bcol][rg * 8];
        pA1 = *(const f16x8*)&xh[0][bcol][32 + rg * 8];
        __syncthreads();  // B3

        if (t == T_STEPS - 1) {   // eager L4(255): its c4 is the extra step's x
            if (wave == 7) {
                do_l4();
                if (lane < 8) xh[0][lane][H] = (_Float16)c4;
            }
            __syncthreads();
            pA0 = *(const f16x8*)&xh[0][bcol][rg * 8];   // re-prefetch (x changed)
            pA1 = *(const f16x8*)&xh[0][bcol][32 + rg * 8];
        }
    }

    // epilogue: layer-4 of the extra step, then output
    if (wave == 7) {
        do_l4();
        if (lane < 8) out[blockIdx.x * 8 + lane] = c4;
    }
}

extern "C" void kernel_launch(void* const* d_in, const int* in_sizes, int n_in,
                              void* d_out, int out_size, void* d_ws, size_t ws_size,
                              hipStream_t stream) {
    const float* input = (const float*)d_in[0];
    const float* w_ih1 = (const float*)d_in[1];
    const float* w_hh1 = (const float*)d_in[2];
    const float* b_ih1 = (const float*)d_in[3];
    const float* b_hh1 = (const float*)d_in[4];
    const float* w_ih2 = (const float*)d_in[5];
    const float* w_hh2 = (const float*)d_in[6];
    const float* b_ih2 = (const float*)d_in[7];
    const float* b_hh2 = (const float*)d_in[8];
    const float* w_ih3 = (const float*)d_in[9];
    const float* w_hh3 = (const float*)d_in[10];
    const float* b_ih3 = (const float*)d_in[11];
    const float* b_hh3 = (const float*)d_in[12];
    const float* w_ih4 = (const float*)d_in[13];
    const float* w_hh4 = (const float*)d_in[14];
    const float* b_ih4 = (const float*)d_in[15];
    const float* b_hh4 = (const float*)d_in[16];

    _Float16* wpa = (_Float16*)d_ws;  // 132 units * 512 halves = 135,168 B

    hipLaunchKernelGGL(prep_mfma, dim3((NUNIT * 64 + 255) / 256), dim3(256), 0, stream,
                       w_ih1, w_hh1, w_ih2, w_hh2, w_ih3, w_hh3, w_ih4, wpa);

    hipLaunchKernelGGL(lstm4_main, dim3(BATCH / 8), dim3(512), 0, stream,
                       input, wpa,
                       b_ih1, b_hh1, b_ih2, b_hh2, b_ih3, b_hh3,
                       w_hh4, b_ih4, b_hh4,
                       (float*)d_out);
}

// Round 9
// 327.866 us; speedup vs baseline: 2.1040x; 1.3457x over previous
//
#include <hip/hip_runtime.h>

// Round 9: cross-step layer pipeline — ONE barrier per step.
// phase(ph) computes L1(ph), L2(ph-1), L3(ph-2), L4(ph-3) concurrently; all LDS
// reads are exactly-1-barrier-old. All 6 h/c vectors parity-double-buffered so
// write/read parities are disjoint every phase (race-free under wave skew).
// Weight A-frags pinned in VGPRs via asm (compiler was re-loading them, r8
// VGPR=84<88). Col-split activations halve transcendental work. Feedback step
// = 4-phase serial epilogue after full drain. WG 512 x 8 batch, grid 256.

typedef _Float16 f16x8 __attribute__((ext_vector_type(8)));
typedef float    f32x4 __attribute__((ext_vector_type(4)));

constexpr int BATCH   = 2048;
constexpr int T_STEPS = 256;
constexpr int H   = 51;
constexpr int NTILE = 13;                 // 16-row tiles (208 padded rows)
constexpr int NUNIT = 5 * NTILE * 2 + 2;  // 130 big + 2 layer-4 units
constexpr int XKP = 80;                   // xh k-stride in halves (160 B)

__device__ __forceinline__ float frcp(float x) { return __builtin_amdgcn_rcpf(x); }
__device__ __forceinline__ float sigmoid_f(float x) { float e = __expf(-x); return frcp(1.f + e); }
__device__ __forceinline__ float tanh_f(float x) {
    float e = __expf(2.f * x);       // ->inf gives 1, ->0 gives -1; no clamp needed
    return 1.f - 2.f * frcp(e + 1.f);
}

#define PIN16(x) { f32x4 _t = __builtin_bit_cast(f32x4, x); asm volatile("" : "+v"(_t)); x = __builtin_bit_cast(f16x8, _t); }
#define PIN4(x)  asm volatile("" : "+v"(x))

// Pack weights into MFMA A-frag layout with gate-interleaved rows (as r7/r8).
// u<130: u=(pm*13+tile)*2+kf; pm: 0=hh1(+w_ih1 col at j=51) 1=ih2 2=hh2 3=ih3 4=hh3
// u=130/131: layer-4 w_ih4 rows 0-3, kf=u-130.
__global__ __launch_bounds__(256) void prep_mfma(
    const float* __restrict__ w_ih1, const float* __restrict__ w_hh1,
    const float* __restrict__ w_ih2, const float* __restrict__ w_hh2,
    const float* __restrict__ w_ih3, const float* __restrict__ w_hh3,
    const float* __restrict__ w_ih4, _Float16* __restrict__ wpa)
{
    int id = blockIdx.x * 256 + threadIdx.x;
    if (id >= NUNIT * 64) return;
    int u = id >> 6, l = id & 63;
    int row16 = l & 15;
    int kbase = ((u & 1) ? 32 : 0) + ((l >> 4) << 3);
    f16x8 v;
    if (u < 130) {
        int pm = u / 26, tile = (u % 26) >> 1;
        const float* W = (pm == 0) ? w_hh1 : (pm == 1) ? w_ih2 : (pm == 2) ? w_hh2
                       : (pm == 3) ? w_ih3 : w_hh3;
        int kh = tile * 4 + (row16 >> 2);
        int q  = row16 & 3;
        bool rv = (kh < H);
        int orow = q * H + kh;
#pragma unroll
        for (int e = 0; e < 8; ++e) {
            int j = kbase + e;
            float val = 0.f;
            if (rv) {
                if (j < H)                  val = W[orow * H + j];
                else if (j == H && pm == 0) val = w_ih1[orow];
            }
            v[e] = (_Float16)val;
        }
    } else {
#pragma unroll
        for (int e = 0; e < 8; ++e) {
            int j = kbase + e;
            v[e] = (_Float16)((row16 < 4 && j < H) ? w_ih4[row16 * H + j] : 0.f);
        }
    }
    *(f16x8*)(wpa + (size_t)u * 512 + l * 8) = v;
}

__global__ __launch_bounds__(512, 2) void lstm4_main(
    const float* __restrict__ input, const _Float16* __restrict__ wpa,
    const float* __restrict__ b_ih1, const float* __restrict__ b_hh1,
    const float* __restrict__ b_ih2, const float* __restrict__ b_hh2,
    const float* __restrict__ b_ih3, const float* __restrict__ b_hh3,
    const float* __restrict__ w_hh4,
    const float* __restrict__ b_ih4, const float* __restrict__ b_hh4,
    float* __restrict__ out)
{
    // vectors: 0=h1(+x at k=51) 1=c1 2=h2 3=c2 4=h3 5=c3; [vec][parity][b][k]
    __shared__ __align__(16) _Float16 xh[6][2][8][XKP];   // 15360 B
    __shared__ float inl[8 * 260];                        //  8320 B

    const int tid  = threadIdx.x;
    const int wave = tid >> 6;
    const int lane = tid & 63;
    const int col  = lane & 15;    // C/D col = batch (cols 8-15 duplicate)
    const int rg   = lane >> 4;    // row-group / k-group
    const int bcol = lane & 7;

    // ---- persistent weight fragments (pinned) ----
    const int tile0 = wave;
    const int tile1 = (wave < 5) ? (8 + wave) : wave;
    const bool two  = (wave < 5);
    auto LF = [&](int pm, int tile, int kf) -> f16x8 {
        int u = (pm * NTILE + tile) * 2 + kf;
        return *(const f16x8*)(wpa + (size_t)u * 512 + lane * 8);
    };
    f16x8 fA_0k0  = LF(0, tile0, 0), fA_0k1  = LF(0, tile0, 1);
    f16x8 fA_1k0  = LF(0, tile1, 0), fA_1k1  = LF(0, tile1, 1);
    f16x8 fI2_0k0 = LF(1, tile0, 0), fI2_0k1 = LF(1, tile0, 1);
    f16x8 fI2_1k0 = LF(1, tile1, 0), fI2_1k1 = LF(1, tile1, 1);
    f16x8 fH2_0k0 = LF(2, tile0, 0), fH2_0k1 = LF(2, tile0, 1);
    f16x8 fH2_1k0 = LF(2, tile1, 0), fH2_1k1 = LF(2, tile1, 1);
    f16x8 fI3_0k0 = LF(3, tile0, 0), fI3_0k1 = LF(3, tile0, 1);
    f16x8 fI3_1k0 = LF(3, tile1, 0), fI3_1k1 = LF(3, tile1, 1);
    f16x8 fH3_0k0 = LF(4, tile0, 0), fH3_0k1 = LF(4, tile0, 1);
    f16x8 fH3_1k0 = LF(4, tile1, 0), fH3_1k1 = LF(4, tile1, 1);
    f16x8 fL4k0 = *(const f16x8*)(wpa + (size_t)130 * 512 + lane * 8);
    f16x8 fL4k1 = *(const f16x8*)(wpa + (size_t)131 * 512 + lane * 8);
    PIN16(fA_0k0);  PIN16(fA_0k1);  PIN16(fA_1k0);  PIN16(fA_1k1);
    PIN16(fI2_0k0); PIN16(fI2_0k1); PIN16(fI2_1k0); PIN16(fI2_1k1);
    PIN16(fH2_0k0); PIN16(fH2_0k1); PIN16(fH2_1k0); PIN16(fH2_1k1);
    PIN16(fI3_0k0); PIN16(fI3_0k1); PIN16(fI3_1k0); PIN16(fI3_1k1);
    PIN16(fH3_0k0); PIN16(fH3_0k1); PIN16(fH3_1k0); PIN16(fH3_1k1);
    PIN16(fL4k0);   PIN16(fL4k1);

    // ---- bias vectors (MFMA C-init; pinned) ----
    const int k0 = tile0 * 4 + rg;
    const int k1 = tile1 * 4 + rg;
    const bool k1v = two && (k1 < H);
    f32x4 cb1v0, cb1v1, cb2v0, cb2v1, cb3v0, cb3v1;
#pragma unroll
    for (int q = 0; q < 4; ++q) {
        cb1v0[q] = b_ih1[q * H + k0] + b_hh1[q * H + k0];
        cb2v0[q] = b_ih2[q * H + k0] + b_hh2[q * H + k0];
        cb3v0[q] = b_ih3[q * H + k0] + b_hh3[q * H + k0];
        cb1v1[q] = k1v ? (b_ih1[q * H + k1] + b_hh1[q * H + k1]) : 0.f;
        cb2v1[q] = k1v ? (b_ih2[q * H + k1] + b_hh2[q * H + k1]) : 0.f;
        cb3v1[q] = k1v ? (b_ih3[q * H + k1] + b_hh3[q * H + k1]) : 0.f;
    }
    PIN4(cb1v0); PIN4(cb1v1); PIN4(cb2v0); PIN4(cb2v1); PIN4(cb3v0); PIN4(cb3v1);
    float bias4v[4], whh4v[4];
#pragma unroll
    for (int q = 0; q < 4; ++q) {
        bias4v[q] = b_ih4[q] + b_hh4[q];
        whh4v[q]  = w_hh4[q];
    }

    // ---- stage input, zero x-vectors, stage x(0) ----
    {
        const float4 iv = *(const float4*)(input + (size_t)blockIdx.x * 2048 + tid * 4);
        *(float4*)(inl + (tid >> 6) * 260 + (tid & 63) * 4) = iv;
    }
    for (int i = tid; i < 6 * 2 * 8 * XKP; i += 512) ((_Float16*)xh)[i] = (_Float16)0.f;
    __syncthreads();
    if (tid < 8) xh[0][1][tid][H] = (_Float16)inl[tid * 260];   // x(0) -> parity 1
    __syncthreads();

    // per-lane states: col<8 -> (k0, b=col); col>=8 -> (k1, b=col-8)
    float c1s = 0.f, c2s = 0.f, c3s = 0.f;
    float h4 = 0.f, c4 = 0.f;   // wave 7, lanes 0-7

    auto mm = [](f16x8 A, f16x8 B, f32x4 C) {
        return __builtin_amdgcn_mfma_f32_16x16x32_f16(A, B, C, 0, 0, 0);
    };
    auto BF = [&](int v, int p, int kb) -> f16x8 {
        return *(const f16x8*)&xh[v][p][bcol][kb * 32 + rg * 8];
    };
    // col-split act+store: col<8 handles acc0/(k0,col), col>=8 acc1/(k1,col-8)
    auto AS = [&](f32x4 a0, f32x4 a1, float& cs, int vh, int vc, int wp) {
        f32x4 a;
#pragma unroll
        for (int q = 0; q < 4; ++q) a[q] = (col < 8) ? a0[q] : a1[q];
        const float i_ = sigmoid_f(a[0]), f_ = sigmoid_f(a[1]);
        const float g_ = tanh_f(a[2]),    o_ = sigmoid_f(a[3]);
        cs = f_ * cs + i_ * g_;
        const float h = o_ * tanh_f(cs);
        const bool st = (col < 8) ? true : (two && k1 < H);
        const int kk = (col < 8) ? k0 : k1;
        if (st) {
            xh[vh][wp][col & 7][kk] = (_Float16)h;
            xh[vc][wp][col & 7][kk] = (_Float16)cs;
        }
    };
    auto L4FIN = [&](f32x4 la) {
        if (lane < 8) {
            const float i_ = sigmoid_f(la[0] + bias4v[0] + whh4v[0] * h4);
            const float f_ = sigmoid_f(la[1] + bias4v[1] + whh4v[1] * h4);
            const float g_ = tanh_f  (la[2] + bias4v[2] + whh4v[2] * h4);
            const float o_ = sigmoid_f(la[3] + bias4v[3] + whh4v[3] * h4);
            c4 = f_ * c4 + i_ * g_;
            h4 = o_ * tanh_f(c4);
        }
    };

    // branchy per-layer runners (fill/drain/epilogue phases only)
    auto runL1 = [&](int rp, int wp) {
        f16x8 b0 = BF(0, rp, 0), b1 = BF(0, rp, 1);
        f32x4 a0 = mm(fA_0k0, b0, cb1v0); a0 = mm(fA_0k1, b1, a0);
        f32x4 a1 = cb1v1;
        if (two) { a1 = mm(fA_1k0, b0, a1); a1 = mm(fA_1k1, b1, a1); }
        AS(a0, a1, c1s, 0, 1, wp);
    };
    auto runL2 = [&](int rx, int rh, int wp) {
        f16x8 x0 = BF(1, rx, 0), x1 = BF(1, rx, 1);
        f16x8 h0 = BF(2, rh, 0), h1f = BF(2, rh, 1);
        f32x4 a0 = mm(fH2_0k0, h0, cb2v0); a0 = mm(fH2_0k1, h1f, a0);
        a0 = mm(fI2_0k0, x0, a0); a0 = mm(fI2_0k1, x1, a0);
        f32x4 a1 = cb2v1;
        if (two) {
            a1 = mm(fH2_1k0, h0, a1); a1 = mm(fH2_1k1, h1f, a1);
            a1 = mm(fI2_1k0, x0, a1); a1 = mm(fI2_1k1, x1, a1);
        }
        AS(a0, a1, c2s, 2, 3, wp);
    };
    auto runL3 = [&](int rx, int rh, int wp) {
        f16x8 x0 = BF(3, rx, 0), x1 = BF(3, rx, 1);
        f16x8 h0 = BF(4, rh, 0), h1f = BF(4, rh, 1);
        f32x4 a0 = mm(fH3_0k0, h0, cb3v0); a0 = mm(fH3_0k1, h1f, a0);
        a0 = mm(fI3_0k0, x0, a0); a0 = mm(fI3_0k1, x1, a0);
        f32x4 a1 = cb3v1;
        if (two) {
            a1 = mm(fH3_1k0, h0, a1); a1 = mm(fH3_1k1, h1f, a1);
            a1 = mm(fI3_1k0, x0, a1); a1 = mm(fI3_1k1, x1, a1);
        }
        AS(a0, a1, c3s, 4, 5, wp);
    };
    auto runL4 = [&](int rp) {
        if (wave == 7) {
            f16x8 b0 = BF(5, rp, 0), b1 = BF(5, rp, 1);
            f32x4 la = {0.f, 0.f, 0.f, 0.f};
            la = mm(fL4k0, b0, la); la = mm(fL4k1, b1, la);
            L4FIN(la);
        }
    };
    auto stageX = [&](int ph) {   // stage x(ph+1) into parity ph&1
        if (wave == 6 && lane < 8 && ph <= 254)
            xh[0][ph & 1][lane][51] = (_Float16)inl[lane * 260 + ph + 1];
    };

    // ---- fill phases 0..2 (branchy) ----
    for (int ph = 0; ph <= 2; ++ph) {
        const int pw = ph & 1;
        runL1(1 - pw, pw);
        if (ph >= 1) runL2(1 - pw, pw, 1 - pw);
        if (ph >= 2) runL3(pw, 1 - pw, pw);
        stageX(ph);
        __syncthreads();
    }

    // ---- steady state: phases 3..255, branch-light single block ----
    for (int ph = 3; ph <= 255; ++ph) {
        const int pw = ph & 1;
        // all common B-frag reads up front (1-barrier-old data)
        f16x8 rA0 = BF(0, 1 - pw, 0), rA1 = BF(0, 1 - pw, 1);      // h1+x
        f16x8 r2x0 = BF(1, 1 - pw, 0), r2x1 = BF(1, 1 - pw, 1);    // c1
        f16x8 r2h0 = BF(2, pw, 0),     r2h1 = BF(2, pw, 1);        // h2
        f16x8 r3x0 = BF(3, pw, 0),     r3x1 = BF(3, pw, 1);        // c2
        f16x8 r3h0 = BF(4, 1 - pw, 0), r3h1 = BF(4, 1 - pw, 1);    // h3
        // acc0 MFMAs (all waves)
        f32x4 a0 = mm(fA_0k0, rA0, cb1v0);  a0 = mm(fA_0k1, rA1, a0);
        f32x4 b0 = mm(fH2_0k0, r2h0, cb2v0); b0 = mm(fH2_0k1, r2h1, b0);
        b0 = mm(fI2_0k0, r2x0, b0);          b0 = mm(fI2_0k1, r2x1, b0);
        f32x4 d0 = mm(fH3_0k0, r3h0, cb3v0); d0 = mm(fH3_0k1, r3h1, d0);
        d0 = mm(fI3_0k0, r3x0, d0);          d0 = mm(fI3_0k1, r3x1, d0);
        f32x4 a1 = cb1v1, b1 = cb2v1, d1 = cb3v1;
        if (wave != 7) {   // second tiles (waves 5-6 compute dummies, unstored)
            a1 = mm(fA_1k0, rA0, a1);  a1 = mm(fA_1k1, rA1, a1);
            b1 = mm(fH2_1k0, r2h0, b1); b1 = mm(fH2_1k1, r2h1, b1);
            b1 = mm(fI2_1k0, r2x0, b1); b1 = mm(fI2_1k1, r2x1, b1);
            d1 = mm(fH3_1k0, r3h0, d1); d1 = mm(fH3_1k1, r3h1, d1);
            d1 = mm(fI3_1k0, r3x0, d1); d1 = mm(fI3_1k1, r3x1, d1);
        } else {           // wave 7: L4(ph-3) instead of dummy tiles
            f16x8 l0 = BF(5, 1 - pw, 0), l1 = BF(5, 1 - pw, 1);
            f32x4 la = {0.f, 0.f, 0.f, 0.f};
            la = mm(fL4k0, l0, la); la = mm(fL4k1, l1, la);
            L4FIN(la);
        }
        // acts + stores (parities: L1->pw, L2->1-pw, L3->pw)
        AS(a0, a1, c1s, 0, 1, pw);
        AS(b0, b1, c2s, 2, 3, 1 - pw);
        AS(d0, d1, c3s, 4, 5, pw);
        stageX(ph);
        __syncthreads();
    }

    // ---- drain phases 256..258 (branchy) ----
    for (int ph = 256; ph <= 258; ++ph) {
        const int pw = ph & 1;
        if (ph <= 256) runL2(1 - pw, pw, 1 - pw);
        if (ph <= 257) runL3(pw, 1 - pw, pw);
        runL4(1 - pw);
        __syncthreads();
    }

    // ---- epilogue: feedback step (x = c4 after 256 input steps) ----
    if (wave == 7 && lane < 8) xh[0][1][lane][51] = (_Float16)c4;
    __syncthreads();
    runL1(1, 0); __syncthreads();       // L1(256): reads h1(255)+x_e, writes parity 0
    runL2(0, 1, 0); __syncthreads();    // L2(256): c1(256) p0, h2(255) p1
    runL3(0, 1, 0); __syncthreads();    // L3(256): c2(256) p0, h3(255) p1
    runL4(0);                           // L4(256): c3(256) p0 -> final c4
    if (wave == 7 && lane < 8) out[blockIdx.x * 8 + lane] = c4;
}

extern "C" void kernel_launch(void* const* d_in, const int* in_sizes, int n_in,
                              void* d_out, int out_size, void* d_ws, size_t ws_size,
                              hipStream_t stream) {
    const float* input = (const float*)d_in[0];
    const float* w_ih1 = (const float*)d_in[1];
    const float* w_hh1 = (const float*)d_in[2];
    const float* b_ih1 = (const float*)d_in[3];
    const float* b_hh1 = (const float*)d_in[4];
    const float* w_ih2 = (const float*)d_in[5];
    const float* w_hh2 = (const float*)d_in[6];
    const float* b_ih2 = (const float*)d_in[7];
    const float* b_hh2 = (const float*)d_in[8];
    const float* w_ih3 = (const float*)d_in[9];
    const float* w_hh3 = (const float*)d_in[10];
    const float* b_ih3 = (const float*)d_in[11];
    const float* b_hh3 = (const float*)d_in[12];
    const float* w_ih4 = (const float*)d_in[13];
    const float* w_hh4 = (const float*)d_in[14];
    const float* b_ih4 = (const float*)d_in[15];
    const float* b_hh4 = (const float*)d_in[16];

    _Float16* wpa = (_Float16*)d_ws;  // 132 units * 512 halves = 135,168 B

    hipLaunchKernelGGL(prep_mfma, dim3((NUNIT * 64 + 255) / 256), dim3(256), 0, stream,
                       w_ih1, w_hh1, w_ih2, w_hh2, w_ih3, w_hh3, w_ih4, wpa);

    hipLaunchKernelGGL(lstm4_main, dim3(BATCH / 8), dim3(512), 0, stream,
                       input, wpa,
                       b_ih1, b_hh1, b_ih2, b_hh2, b_ih3, b_hh3,
                       w_hh4, b_ih4, b_hh4,
                       (float*)d_out);
}